// Round 14
// baseline (924.061 us; speedup 1.0000x reference)
//
#include <hip/hip_runtime.h>

// WeightOnlyInt4Linear: out[8192,11008] = x[8192,4096] @ dequant(packed int4 W)
// (1) x -> bf16, (2) W int4 -> bf16 [N][K] transposed, (3) bf16 MFMA GEMM.
// R14: 128x128 tile, 4 waves (2x2), 64x64/wave (acc 64 regs), 32KB LDS,
// __launch_bounds__(256,3) -> 3 blocks/CU (3 waves/SIMD TLP). Minimal schedule:
// per tile {WAITV(0);BAR; read A8+B8; MFMA16; BAR; stage 8[t+1]; MFMA16}.
// WAR: stages follow the BAR that proves all waves' reads drained. Same swizzle.

#define M_DIM 8192
#define K_DIM 4096
#define N_DIM 11008
#define BM 128
#define BN 128
#define BK 64
#define NKT (K_DIM / BK)  // 64

typedef unsigned short u16;
typedef __bf16 bf16x8 __attribute__((ext_vector_type(8)));
typedef float floatx4 __attribute__((ext_vector_type(4)));
typedef u16 u16x8 __attribute__((ext_vector_type(8)));
typedef u16 u16x4 __attribute__((ext_vector_type(4)));

typedef __attribute__((address_space(1))) const void* gcvp;
typedef __attribute__((address_space(3))) void* svp;

static __device__ __forceinline__ u16 f2b(float f) {
  union { float f; unsigned u; } v;
  v.f = f;
  unsigned r = v.u + 0x7FFFu + ((v.u >> 16) & 1u);  // RNE, finite inputs
  return (u16)(r >> 16);
}

// ---------------- kernel 1: x f32 -> bf16 ----------------
__global__ __launch_bounds__(256) void cvt_x_kernel(const float* __restrict__ x,
                                                    u16* __restrict__ xb) {
  int i = blockIdx.x * 256 + threadIdx.x;
  const int n4 = (M_DIM * K_DIM) / 4;
  const int stride = 2048 * 256;
  for (; i < n4; i += stride) {
    const float4 v = reinterpret_cast<const float4*>(x)[i];
    u16x4 r;
    r[0] = f2b(v.x); r[1] = f2b(v.y); r[2] = f2b(v.z); r[3] = f2b(v.w);
    reinterpret_cast<u16x4*>(xb)[i] = r;
  }
}

// ---------------- kernel 2: int4 W -> bf16 W^T [N][K] ----------------
__global__ __launch_bounds__(256) void dequant_w_kernel(const int* __restrict__ pw,
                                                        const float* __restrict__ sc,
                                                        const float* __restrict__ zr,
                                                        u16* __restrict__ wbt) {
  __shared__ int tile[64][65];
  const int t = threadIdx.x;
  const int o0 = blockIdx.x * 64;
  const int kw0 = blockIdx.y * 64;
#pragma unroll
  for (int r = 0; r < 16; ++r) {
    const int kw = r * 4 + (t >> 6);
    const int o = t & 63;
    tile[kw][o] = pw[(kw0 + kw) * N_DIM + o0 + o];
  }
  __syncthreads();
  const int kwl = t & 63;
  const int g = (kw0 + kwl) >> 4;
  const int obase = (t >> 6) * 16;
  for (int it = 0; it < 16; ++it) {
    const int ol = obase + it;
    const int o = o0 + ol;
    const float s = sc[o * 32 + g];
    const float z = zr[o * 32 + g];
    const float b = -z * s;
    const int word = tile[kwl][ol];
    u16x8 r;
#pragma unroll
    for (int j = 0; j < 8; ++j) {
      const float q = (float)((word >> (4 * j)) & 0xF);
      r[j] = f2b(fmaf(q, s, b));
    }
    *reinterpret_cast<u16x8*>(&wbt[(size_t)o * K_DIM + (size_t)(kw0 + kwl) * 8]) = r;
  }
}

// ---------------- kernel 3: 128x128 3-blocks/CU bf16 MFMA GEMM ----------------
// 256 thr = 4 waves (wm=w>>1, wn=w&1); per wave 64x64 out = 4x4 frags 16x16x32.
// LDS: A[128][64] @0 + B[128][64] @8192 = 32 KiB, 16B-slot swizzle ^(row&7).

#define WAITV0                                               \
  asm volatile("s_waitcnt vmcnt(0)" ::: "memory");           \
  __builtin_amdgcn_sched_barrier(0)
#define BAR __builtin_amdgcn_s_barrier()

__global__ __launch_bounds__(256, 3) void gemm_kernel(const u16* __restrict__ xb,
                                                      const u16* __restrict__ wbt,
                                                      float* __restrict__ out) {
  __shared__ __align__(16) u16 lds[(BM + BN) * BK];  // 32768 B: A @0, B @8192

  const int tid = threadIdx.x;
  const int w = tid >> 6;
  const int l = tid & 63;
  const int wm = w >> 1;  // 0..1
  const int wn = w & 1;   // 0..1

  // bijective XCD swizzle: 5504 = 8*688
  const int bid = blockIdx.x;
  const int wg = (bid & 7) * 688 + (bid >> 3);
  const int NT = N_DIM / BN;  // 86
  const int m0 = (wg / NT) * BM;
  const int n0 = (wg % NT) * BN;

  // ---- staging: unit = 32 rows; thread -> row = u*32 + (tid>>3), slot = tid&7
  const int sr = tid >> 3;                       // 0..31
  const int scc = ((tid & 7) ^ (sr & 7)) * 8;    // involution slot^(row&7)
  const u16* srcA = xb + (size_t)(m0 + sr) * K_DIM + scc;
  const u16* srcB = wbt + (size_t)(n0 + sr) * K_DIM + scc;

#define STAGEU(op, u, t)                                                       \
  __builtin_amdgcn_global_load_lds(                                            \
      gcvp(((op) ? srcB : srcA) + (size_t)((u) * 32) * K_DIM + (t) * 64),      \
      svp(&lds[(op) * 8192 + ((u) * 32 + w * 8) * 64]), 16, 0, 0)

#define STAGEALL(t)                                                            \
  do {                                                                         \
    STAGEU(0, 0, t); STAGEU(0, 1, t); STAGEU(0, 2, t); STAGEU(0, 3, t);        \
    STAGEU(1, 0, t); STAGEU(1, 1, t); STAGEU(1, 2, t); STAGEU(1, 3, t);        \
  } while (0)

  // ---- fragment bases (16x16 pattern, measured conflict-free); kk=1 = ^32
  const int swz = ((l >> 4) ^ (l & 7)) * 8;
  const int baseA = (wm * 64 + (l & 15)) * 64 + swz;
  const int baseB = 8192 + (wn * 64 + (l & 15)) * 64 + swz;
  const u16* lp = &lds[0];

  bf16x8 a[4][2], b[4][2];

#define LDALL                                                                           \
  do {                                                                                  \
    _Pragma("unroll") for (int _m = 0; _m < 4; ++_m) {                                  \
      const int _e = baseA + _m * 1024;                                                 \
      a[_m][0] = *reinterpret_cast<const bf16x8*>(&lp[_e]);                             \
      a[_m][1] = *reinterpret_cast<const bf16x8*>(&lp[_e ^ 32]);                        \
    }                                                                                   \
    _Pragma("unroll") for (int _n = 0; _n < 4; ++_n) {                                  \
      const int _e = baseB + _n * 1024;                                                 \
      b[_n][0] = *reinterpret_cast<const bf16x8*>(&lp[_e]);                             \
      b[_n][1] = *reinterpret_cast<const bf16x8*>(&lp[_e ^ 32]);                        \
    }                                                                                   \
  } while (0)

  floatx4 acc[4][4] = {};

#define QMFMA(U)                                                                        \
  do {                                                                                  \
    __builtin_amdgcn_s_setprio(1);                                                     \
    _Pragma("unroll") for (int _m = 0; _m < 4; ++_m)                                    \
      _Pragma("unroll") for (int _n = 0; _n < 2; ++_n)                                  \
        _Pragma("unroll") for (int _k = 0; _k < 2; ++_k)                                \
          acc[_m][(U) * 2 + _n] = __builtin_amdgcn_mfma_f32_16x16x32_bf16(              \
              a[_m][_k], b[(U) * 2 + _n][_k], acc[_m][(U) * 2 + _n], 0, 0, 0);          \
    __builtin_amdgcn_s_setprio(0);                                                     \
  } while (0)

  // ---- prologue: stage tile 0 (8 loads) ----
  STAGEALL(0);

  // ---- main loop: 2 barriers + 1 vmcnt per K-tile ----
  // p0: WAITV(0) drains tile t's 8 loads (issued t-1 p1); BAR publishes.
  // reads (16 ds_read_b128) + MFMA ni01. p1's BAR proves all waves' reads
  // drained (compiler lgkm before MFMA issue, program order) -> stages safe.
#pragma unroll 2
  for (int t = 0; t < NKT - 1; ++t) {
    WAITV0; BAR;
    LDALL;
    QMFMA(0);
    BAR;
    STAGEALL(t + 1);
    QMFMA(1);
  }
  // ---- peel t = NKT-1: no stages ----
  {
    WAITV0; BAR;
    LDALL;
    QMFMA(0);
    QMFMA(1);
  }

  // ---- epilogue: C/D map col = l&15, row = (l>>4)*4 + j (verified R1/R2) ----
  const int orow0 = m0 + wm * 64 + (l >> 4) * 4;
  const int ocol0 = n0 + wn * 64 + (l & 15);
#pragma unroll
  for (int mi = 0; mi < 4; ++mi)
#pragma unroll
    for (int j = 0; j < 4; ++j) {
      float* op = out + (size_t)(orow0 + mi * 16 + j) * N_DIM + ocol0;
#pragma unroll
      for (int ni = 0; ni < 4; ++ni) op[ni * 16] = acc[mi][ni][j];
    }
}

// ---------------- fallback: fly-dequant (ws too small) ----------------
__global__ __launch_bounds__(256) void gemm_naive(const float* __restrict__ x,
                                                  const int* __restrict__ pw,
                                                  const float* __restrict__ sc,
                                                  const float* __restrict__ zr,
                                                  float* __restrict__ out) {
  const int idx = blockIdx.x * 256 + threadIdx.x;
  if (idx >= M_DIM * N_DIM) return;
  const int m = idx / N_DIM, o = idx % N_DIM;
  const float* xr = x + (size_t)m * K_DIM;
  float acc = 0.f;
  for (int g = 0; g < 32; ++g) {
    const float s = sc[o * 32 + g];
    const float z = zr[o * 32 + g];
    const float b = -z * s;
    for (int kw = g * 16; kw < g * 16 + 16; ++kw) {
      const int word = pw[kw * N_DIM + o];
#pragma unroll
      for (int j = 0; j < 8; ++j) {
        const float q = (float)((word >> (4 * j)) & 0xF);
        acc += xr[kw * 8 + j] * fmaf(q, s, b);
      }
    }
  }
  out[idx] = acc;
}

extern "C" void kernel_launch(void* const* d_in, const int* in_sizes, int n_in,
                              void* d_out, int out_size, void* d_ws, size_t ws_size,
                              hipStream_t stream) {
  (void)in_sizes; (void)n_in; (void)out_size;
  const float* x = (const float*)d_in[0];
  const int* pw = (const int*)d_in[1];
  const float* sc = (const float*)d_in[2];
  const float* zr = (const float*)d_in[3];
  float* out = (float*)d_out;

  const size_t need = ((size_t)M_DIM * K_DIM + (size_t)N_DIM * K_DIM) * 2;
  if (ws_size >= need) {
    u16* xb = (u16*)d_ws;
    u16* wbt = xb + (size_t)M_DIM * K_DIM;
    cvt_x_kernel<<<2048, 256, 0, stream>>>(x, xb);
    dequant_w_kernel<<<dim3(N_DIM / 64, (K_DIM / 8) / 64), 256, 0, stream>>>(pw, sc, zr, wbt);
    gemm_kernel<<<(M_DIM / BM) * (N_DIM / BN), 256, 0, stream>>>(xb, wbt, out);
  } else {
    gemm_naive<<<(M_DIM * N_DIM + 255) / 256, 256, 0, stream>>>(x, pw, sc, zr, out);
  }
}

// Round 15
// 684.202 us; speedup vs baseline: 1.3506x; 1.3506x over previous
//
#include <hip/hip_runtime.h>

// WeightOnlyInt4Linear: out[8192,11008] = x[8192,4096] @ dequant(packed int4 W)
// (1) x -> bf16, (2) W int4 -> bf16 [N][K] transposed, (3) bf16 MFMA GEMM.
// R15 = exact revert to R12 (measured best: GEMM ~635us, MfmaUtil 64.4%).
// 256x128 tile, 256 thr (4 waves 2Mx2N), SINGLE-buffer 48 KB LDS ->
// 2 blocks/CU co-resident; grid 2752=8*344 -> tail 2.3%. Phase-top waits.
// 12 loads/tile ledger: p0 WAITV(6) retires AS0+BU0[t]; p1 WAITV(4) retires
// BU1[t]; p2 WAITV(6) retires AS1[t]. Stages 6/2/4 at p1/p2/p3 post-BAR.
// R14 lesson: 128^2 tile is HBM-infeasible (FETCH 2x); 32x32 MFMA shape has
// intrinsic 4-way LDS conflict in row-major [row][64] layout. This structure
// is the converged plain-HIP optimum (4 nulls + 2 regressions around it).

#define M_DIM 8192
#define K_DIM 4096
#define N_DIM 11008
#define BM 256
#define BN 128
#define BK 64
#define NKT (K_DIM / BK)  // 64

typedef unsigned short u16;
typedef __bf16 bf16x8 __attribute__((ext_vector_type(8)));
typedef float floatx4 __attribute__((ext_vector_type(4)));
typedef u16 u16x8 __attribute__((ext_vector_type(8)));
typedef u16 u16x4 __attribute__((ext_vector_type(4)));

typedef __attribute__((address_space(1))) const void* gcvp;
typedef __attribute__((address_space(3))) void* svp;

static __device__ __forceinline__ u16 f2b(float f) {
  union { float f; unsigned u; } v;
  v.f = f;
  unsigned r = v.u + 0x7FFFu + ((v.u >> 16) & 1u);  // RNE, finite inputs
  return (u16)(r >> 16);
}

// ---------------- kernel 1: x f32 -> bf16 ----------------
__global__ __launch_bounds__(256) void cvt_x_kernel(const float* __restrict__ x,
                                                    u16* __restrict__ xb) {
  int i = blockIdx.x * 256 + threadIdx.x;
  const int n4 = (M_DIM * K_DIM) / 4;
  const int stride = 2048 * 256;
  for (; i < n4; i += stride) {
    const float4 v = reinterpret_cast<const float4*>(x)[i];
    u16x4 r;
    r[0] = f2b(v.x); r[1] = f2b(v.y); r[2] = f2b(v.z); r[3] = f2b(v.w);
    reinterpret_cast<u16x4*>(xb)[i] = r;
  }
}

// ---------------- kernel 2: int4 W -> bf16 W^T [N][K] ----------------
__global__ __launch_bounds__(256) void dequant_w_kernel(const int* __restrict__ pw,
                                                        const float* __restrict__ sc,
                                                        const float* __restrict__ zr,
                                                        u16* __restrict__ wbt) {
  __shared__ int tile[64][65];
  const int t = threadIdx.x;
  const int o0 = blockIdx.x * 64;
  const int kw0 = blockIdx.y * 64;
#pragma unroll
  for (int r = 0; r < 16; ++r) {
    const int kw = r * 4 + (t >> 6);
    const int o = t & 63;
    tile[kw][o] = pw[(kw0 + kw) * N_DIM + o0 + o];
  }
  __syncthreads();
  const int kwl = t & 63;
  const int g = (kw0 + kwl) >> 4;
  const int obase = (t >> 6) * 16;
  for (int it = 0; it < 16; ++it) {
    const int ol = obase + it;
    const int o = o0 + ol;
    const float s = sc[o * 32 + g];
    const float z = zr[o * 32 + g];
    const float b = -z * s;
    const int word = tile[kwl][ol];
    u16x8 r;
#pragma unroll
    for (int j = 0; j < 8; ++j) {
      const float q = (float)((word >> (4 * j)) & 0xF);
      r[j] = f2b(fmaf(q, s, b));
    }
    *reinterpret_cast<u16x8*>(&wbt[(size_t)o * K_DIM + (size_t)(kw0 + kwl) * 8]) = r;
  }
}

// ---------------- kernel 3: 256x128 single-buffer bf16 MFMA GEMM ----------------
// 256 thr = 4 waves (wm=w>>1, wn=w&1); per wave 128x64 out = 8x4 frags 16x16x32.
// LDS: A[256][64] (32KB) + B[128][64] (16KB), 16B-slot swizzle ^(row&7).
// A units 0..7 (32 rows): AS0={0,1,4,5} read p0; AS1={2,3,6,7} read p2.
// B units 0..3: BU0={0,2} read p0, BU1={1,3} read p1.

#define WAITL0                                               \
  asm volatile("s_waitcnt lgkmcnt(0)" ::: "memory");         \
  __builtin_amdgcn_sched_barrier(0)
#define WAITV(n)                                             \
  asm volatile("s_waitcnt vmcnt(" #n ")" ::: "memory");      \
  __builtin_amdgcn_sched_barrier(0)
#define BAR __builtin_amdgcn_s_barrier()

__global__ __launch_bounds__(256, 2) void gemm_kernel(const u16* __restrict__ xb,
                                                      const u16* __restrict__ wbt,
                                                      float* __restrict__ out) {
  __shared__ __align__(16) u16 lds[(BM + BN) * BK];  // 49152 B: A @0, B @16384

  const int tid = threadIdx.x;
  const int w = tid >> 6;
  const int l = tid & 63;
  const int wm = w >> 1;  // 0..1
  const int wn = w & 1;   // 0..1

  // bijective XCD swizzle: 2752 = 8*344
  const int bid = blockIdx.x;
  const int wg = (bid & 7) * 344 + (bid >> 3);
  const int NT = N_DIM / BN;  // 86
  const int m0 = (wg / NT) * BM;
  const int n0 = (wg % NT) * BN;

  // ---- staging: unit = 32 rows; thread -> row = u*32 + (tid>>3), slot = tid&7
  const int sr = tid >> 3;                       // 0..31
  const int scc = ((tid & 7) ^ (sr & 7)) * 8;    // involution slot^(row&7)
  const u16* srcA = xb + (size_t)(m0 + sr) * K_DIM + scc;
  const u16* srcB = wbt + (size_t)(n0 + sr) * K_DIM + scc;

#define STAGEU(op, u, t)                                                       \
  __builtin_amdgcn_global_load_lds(                                            \
      gcvp(((op) ? srcB : srcA) + (size_t)((u) * 32) * K_DIM + (t) * 64),      \
      svp(&lds[(op) * 16384 + ((u) * 32 + w * 8) * 64]), 16, 0, 0)

  // ---- fragment bases (identical formulas to R7); kk=1 addr = kk=0 ^ 32
  const int swz = ((l >> 4) ^ (l & 7)) * 8;
  const int baseA = (wm * 128 + (l & 15)) * 64 + swz;
  const int baseB = 16384 + (wn * 64 + (l & 15)) * 64 + swz;
  const u16* lp = &lds[0];

  bf16x8 a[4][2], b0[2][2], b1[2][2];

#define LDA(S)                                                                          \
  do {                                                                                  \
    _Pragma("unroll") for (int _m = 0; _m < 4; ++_m) {                                  \
      const int _e = baseA + ((S) * 4 + _m) * 1024;                                     \
      a[_m][0] = *reinterpret_cast<const bf16x8*>(&lp[_e]);                             \
      a[_m][1] = *reinterpret_cast<const bf16x8*>(&lp[_e ^ 32]);                        \
    }                                                                                   \
  } while (0)
#define LDB(BA, U)                                                                      \
  do {                                                                                  \
    _Pragma("unroll") for (int _n = 0; _n < 2; ++_n) {                                  \
      const int _e = baseB + ((U) * 2 + _n) * 1024;                                     \
      BA[_n][0] = *reinterpret_cast<const bf16x8*>(&lp[_e]);                            \
      BA[_n][1] = *reinterpret_cast<const bf16x8*>(&lp[_e ^ 32]);                       \
    }                                                                                   \
  } while (0)

  floatx4 acc[8][4] = {};

#define QMFMA(S, BA, U)                                                                 \
  do {                                                                                  \
    __builtin_amdgcn_s_setprio(1);                                                     \
    _Pragma("unroll") for (int _m = 0; _m < 4; ++_m)                                    \
      _Pragma("unroll") for (int _n = 0; _n < 2; ++_n)                                  \
        _Pragma("unroll") for (int _k = 0; _k < 2; ++_k)                                \
          acc[(S) * 4 + _m][(U) * 2 + _n] = __builtin_amdgcn_mfma_f32_16x16x32_bf16(    \
              a[_m][_k], BA[_n][_k], acc[(S) * 4 + _m][(U) * 2 + _n], 0, 0, 0);         \
    __builtin_amdgcn_s_setprio(0);                                                     \
  } while (0)

  // ---- prologue: tile 0 in ledger order: AS0+BU0 (6), BU1 (2), AS1 (4) ----
  STAGEU(0, 0, 0); STAGEU(0, 1, 0); STAGEU(0, 4, 0); STAGEU(0, 5, 0);
  STAGEU(1, 0, 0); STAGEU(1, 2, 0);
  STAGEU(1, 1, 0); STAGEU(1, 3, 0);
  STAGEU(0, 2, 0); STAGEU(0, 3, 0); STAGEU(0, 6, 0); STAGEU(0, 7, 0);

  // ---- main loop: t in [0, NKT-2]; waits at phase top, reads after ----
  // Ledger: p0 top outstanding=12 -> WAITV(6) retires AS0[t],BU0[t].
  //         p1 top 6 -> WAITV(4) retires BU1[t]; stage +6 -> 10.
  //         p2 top 10 -> WAITV(6) retires AS1[t]; stage +2 -> 8.
  //         p3: stage +4 -> 12.  WAR: every stage follows the BAR after its
  //         region's last-read WAITL0 (p0->p1, p1->p2, p2->p3).
  for (int t = 0; t < NKT - 1; ++t) {
    // p0: confirm+publish AS0,BU0[t]; read A-S0 + B-U0
    WAITV(6); BAR;
    LDA(0);
    LDB(b0, 0);
    WAITL0;
    QMFMA(0, b0, 0);
    // p1: confirm BU1[t]; BAR also proves p0 reads drained; stage AS0+BU0[t+1]
    WAITV(4); BAR;
    STAGEU(0, 0, t + 1); STAGEU(0, 1, t + 1); STAGEU(0, 4, t + 1); STAGEU(0, 5, t + 1);
    STAGEU(1, 0, t + 1); STAGEU(1, 2, t + 1);
    LDB(b1, 1);
    WAITL0;
    QMFMA(0, b1, 1);
    // p2: confirm AS1[t]; BAR proves p1 reads drained; stage BU1[t+1]
    WAITV(6); BAR;
    STAGEU(1, 1, t + 1); STAGEU(1, 3, t + 1);
    LDA(1);
    WAITL0;
    QMFMA(1, b0, 0);
    // p3: BAR proves p2 reads drained; stage AS1[t+1]
    BAR;
    STAGEU(0, 2, t + 1); STAGEU(0, 3, t + 1); STAGEU(0, 6, t + 1); STAGEU(0, 7, t + 1);
    QMFMA(1, b1, 1);
  }

  // ---- peel t = NKT-1: no stages; drain 6 -> 4 -> 0 ----
  {
    WAITV(6); BAR;
    LDA(0);
    LDB(b0, 0);
    WAITL0;
    QMFMA(0, b0, 0);
    WAITV(4); BAR;
    LDB(b1, 1);
    WAITL0;
    QMFMA(0, b1, 1);
    WAITV(0); BAR;
    LDA(1);
    WAITL0;
    QMFMA(1, b0, 0);
    QMFMA(1, b1, 1);
  }

  // ---- epilogue: C/D map col = l&15, row = (l>>4)*4 + j (verified R1/R2) ----
  const int orow0 = m0 + wm * 128 + (l >> 4) * 4;
  const int ocol0 = n0 + wn * 64 + (l & 15);
#pragma unroll
  for (int mi = 0; mi < 8; ++mi)
#pragma unroll
    for (int j = 0; j < 4; ++j) {
      float* op = out + (size_t)(orow0 + mi * 16 + j) * N_DIM + ocol0;
#pragma unroll
      for (int ni = 0; ni < 4; ++ni) op[ni * 16] = acc[mi][ni][j];
    }
}

// ---------------- fallback: fly-dequant (ws too small) ----------------
__global__ __launch_bounds__(256) void gemm_naive(const float* __restrict__ x,
                                                  const int* __restrict__ pw,
                                                  const float* __restrict__ sc,
                                                  const float* __restrict__ zr,
                                                  float* __restrict__ out) {
  const int idx = blockIdx.x * 256 + threadIdx.x;
  if (idx >= M_DIM * N_DIM) return;
  const int m = idx / N_DIM, o = idx % N_DIM;
  const float* xr = x + (size_t)m * K_DIM;
  float acc = 0.f;
  for (int g = 0; g < 32; ++g) {
    const float s = sc[o * 32 + g];
    const float z = zr[o * 32 + g];
    const float b = -z * s;
    for (int kw = g * 16; kw < g * 16 + 16; ++kw) {
      const int word = pw[kw * N_DIM + o];
#pragma unroll
      for (int j = 0; j < 8; ++j) {
        const float q = (float)((word >> (4 * j)) & 0xF);
        acc += xr[kw * 8 + j] * fmaf(q, s, b);
      }
    }
  }
  out[idx] = acc;
}

extern "C" void kernel_launch(void* const* d_in, const int* in_sizes, int n_in,
                              void* d_out, int out_size, void* d_ws, size_t ws_size,
                              hipStream_t stream) {
  (void)in_sizes; (void)n_in; (void)out_size;
  const float* x = (const float*)d_in[0];
  const int* pw = (const int*)d_in[1];
  const float* sc = (const float*)d_in[2];
  const float* zr = (const float*)d_in[3];
  float* out = (float*)d_out;

  const size_t need = ((size_t)M_DIM * K_DIM + (size_t)N_DIM * K_DIM) * 2;
  if (ws_size >= need) {
    u16* xb = (u16*)d_ws;
    u16* wbt = xb + (size_t)M_DIM * K_DIM;
    cvt_x_kernel<<<2048, 256, 0, stream>>>(x, xb);
    dequant_w_kernel<<<dim3(N_DIM / 64, (K_DIM / 8) / 64), 256, 0, stream>>>(pw, sc, zr, wbt);
    gemm_kernel<<<(M_DIM / BM) * (N_DIM / BN), 256, 0, stream>>>(xb, wbt, out);
  } else {
    gemm_naive<<<(M_DIM * N_DIM + 255) / 256, 256, 0, stream>>>(x, pw, sc, zr, out);
  }
}